// Round 8
// baseline (320.385 us; speedup 1.0000x reference)
//
#include <hip/hip_runtime.h>
#include <hip/hip_bf16.h>

// EdgePredict: out = softmax((h[u]*h[v]) @ W1 @ W2 @ W3 + biases)
// R0: linear MLP chain collapses to wd[256] + bd; softmax2 = sigmoid(diff).
// R2: f16 table in ws halves gather bytes.
// R4: MFMA dot products, 16 edges/wave-group -> edge kernel at the 64B-line
//     request ceiling (16.25 lines/edge @ 117 G lines/s).
// R5/R6: reorder passes (sort/binning) cost >=100 us to save 35 -> dead end.
// R7 post-mortem: nt-LOAD of fp32 h helps prep; nt-STORE of the table hurt
//     the edge kernel (evict-first lines lose L2/L3 residency): 139->144 us.
// R8: revert nt-store; prep widened to 64 B/thread-iter (4 independent
//     nt-loads for MLP). Edge kernel = exact R4 structure.

#define D 256

typedef _Float16 half8 __attribute__((ext_vector_type(8)));
typedef float float4v __attribute__((ext_vector_type(4)));

// ---------------------------------------------------------------------------
// prep: collapse weights (block 0) + f32 -> f16 table.
// ws layout: [0,1152) wc f32 (wd[256], bd at 256); [1280,1792) wdf f16;
//            [2048,...) f16 table, 512 B/row.
// ---------------------------------------------------------------------------
__global__ __launch_bounds__(256) void prep(
    const float4v* __restrict__ h, half8* __restrict__ tb, int nv16,
    const float* __restrict__ W1, const float* __restrict__ b1,
    const float* __restrict__ W2, const float* __restrict__ b2,
    const float* __restrict__ W3, const float* __restrict__ b3,
    float* __restrict__ wc, _Float16* __restrict__ wdf)
{
    if (blockIdx.x == 0) {
        __shared__ float T[128][2];  // T = W2 @ W3
        const int t = threadIdx.x;
        {
            const int j = t >> 1, c = t & 1;
            float s = 0.f;
            #pragma unroll 8
            for (int k = 0; k < 64; ++k) s += W2[j * 64 + k] * W3[k * 2 + c];
            T[j][c] = s;
        }
        __syncthreads();
        float s0 = 0.f, s1 = 0.f;
        #pragma unroll 8
        for (int j = 0; j < 128; ++j) {
            const float w = W1[t * 128 + j];
            s0 += w * T[j][0];
            s1 += w * T[j][1];
        }
        const float wd = s1 - s0;
        wc[t]  = wd;
        wdf[t] = (_Float16)wd;
        if (t == 0) {
            float f0 = b3[0], f1 = b3[1];
            for (int j = 0; j < 128; ++j) { f0 += b1[j] * T[j][0]; f1 += b1[j] * T[j][1]; }
            for (int k = 0; k < 64; ++k)  { f0 += b2[k] * W3[k * 2 + 0]; f1 += b2[k] * W3[k * 2 + 1]; }
            wc[256] = f1 - f0;  // bd
        }
    }

    // 64 B in (4 independent nt dwordx4 loads), 32 B out (2 regular stores)
    const int gstride = gridDim.x * blockDim.x;
    for (int i = blockIdx.x * blockDim.x + threadIdx.x; i < nv16; i += gstride) {
        const float4v f0 = __builtin_nontemporal_load(&h[4 * i]);
        const float4v f1 = __builtin_nontemporal_load(&h[4 * i + 1]);
        const float4v f2 = __builtin_nontemporal_load(&h[4 * i + 2]);
        const float4v f3 = __builtin_nontemporal_load(&h[4 * i + 3]);
        half8 o0, o1;
        o0[0] = (_Float16)f0.x; o0[1] = (_Float16)f0.y;
        o0[2] = (_Float16)f0.z; o0[3] = (_Float16)f0.w;
        o0[4] = (_Float16)f1.x; o0[5] = (_Float16)f1.y;
        o0[6] = (_Float16)f1.z; o0[7] = (_Float16)f1.w;
        o1[0] = (_Float16)f2.x; o1[1] = (_Float16)f2.y;
        o1[2] = (_Float16)f2.z; o1[3] = (_Float16)f2.w;
        o1[4] = (_Float16)f3.x; o1[5] = (_Float16)f3.y;
        o1[6] = (_Float16)f3.z; o1[7] = (_Float16)f3.w;
        tb[2 * i]     = o0;   // regular stores: table stays cache-resident
        tb[2 * i + 1] = o1;
    }
}

// ---------------------------------------------------------------------------
// MFMA edge kernel (R4 structure, measured at the line-request ceiling):
// 16 edges per wave-group. A[m][k] = tbl[u_m][k]*wd[k] (m=lane&15,
// k=quad*8+j), B[k][n] = tbl[v_n][k]. Logit-diffs = diag(C): lane with
// quad==(m>>2), reg m&3.
// ---------------------------------------------------------------------------
__global__ __launch_bounds__(256) void edge_mfma(
    const _Float16* __restrict__ tbl, const int2* __restrict__ edges,
    const float* __restrict__ wc, const _Float16* __restrict__ wdf,
    float2* __restrict__ out, int E, int ngroups)
{
    const int lane = threadIdx.x & 63;
    const int m    = lane & 15;
    const int quad = lane >> 4;
    const int wid  = blockIdx.x * (blockDim.x >> 6) + (threadIdx.x >> 6);
    const int nw   = gridDim.x * (blockDim.x >> 6);

    const float bd = wc[256];
    const bool diag = (quad == (m >> 2));

    // loop-invariant wd fragments (32 VGPRs)
    half8 wq[8];
    {
        const half8* wp = (const half8*)(wdf + quad * 8);
        #pragma unroll
        for (int s = 0; s < 8; ++s) wq[s] = wp[4 * s];
    }

    for (int g = wid; g < ngroups; g += nw) {
        const int em = g * 16 + m;
        const int2 ed = edges[min(em, E - 1)];
        const half8* pa = (const half8*)(tbl + (size_t)ed.x * D + quad * 8);
        const half8* pb = (const half8*)(tbl + (size_t)ed.y * D + quad * 8);

        float4v acc = {0.f, 0.f, 0.f, 0.f};
        #pragma unroll
        for (int s = 0; s < 8; ++s) {
            const half8 a = pa[4 * s] * wq[s];   // 4x v_pk_mul_f16
            const half8 b = pb[4 * s];
            acc = __builtin_amdgcn_mfma_f32_16x16x32_f16(a, b, acc, 0, 0, 0);
        }

        if (diag && em < E) {
            const float d  = acc[m & 3] + bd;
            const float p1 = 1.0f / (1.0f + __expf(-d));
            out[em] = make_float2(1.0f - p1, p1);
        }
    }
}

// ---------------------------------------------------------------------------
// Fallback: fp32 gather + wave reduction (ws too small for the table)
// ---------------------------------------------------------------------------
__global__ __launch_bounds__(256) void edge_predict_f32(
    const float* __restrict__ h, const int2* __restrict__ edges,
    const float* __restrict__ wc, float2* __restrict__ out, int E)
{
    const int lane = threadIdx.x & 63;
    const int wid  = blockIdx.x * (blockDim.x >> 6) + (threadIdx.x >> 6);
    const int nw   = gridDim.x * (blockDim.x >> 6);
    const float4 wd = ((const float4*)wc)[lane];
    const float  bd = wc[256];
    for (int e = wid; e < E; e += nw) {
        const int2 ed = edges[e];
        const float4 a = ((const float4*)(h + (size_t)ed.x * D))[lane];
        const float4 b = ((const float4*)(h + (size_t)ed.y * D))[lane];
        float d = a.x * b.x * wd.x + a.y * b.y * wd.y + a.z * b.z * wd.z + a.w * b.w * wd.w;
        #pragma unroll
        for (int mm = 32; mm > 0; mm >>= 1) d += __shfl_xor(d, mm, 64);
        if (lane == 0) {
            const float p1 = 1.0f / (1.0f + __expf(-(d + bd)));
            out[e] = make_float2(1.0f - p1, p1);
        }
    }
}

// ---------------------------------------------------------------------------
extern "C" void kernel_launch(void* const* d_in, const int* in_sizes, int n_in,
                              void* d_out, int out_size, void* d_ws, size_t ws_size,
                              hipStream_t stream)
{
    const float* h     = (const float*)d_in[0];
    const int2*  edges = (const int2*)d_in[1];
    const float* W1    = (const float*)d_in[2];
    const float* b1    = (const float*)d_in[3];
    const float* W2    = (const float*)d_in[4];
    const float* b2    = (const float*)d_in[5];
    const float* W3    = (const float*)d_in[6];
    const float* b3    = (const float*)d_in[7];
    float2* out = (float2*)d_out;

    const int nNodes = in_sizes[0] / D;
    const int E      = in_sizes[1] / 2;
    const int nv16   = nNodes * (D / 16);

    float*     wc  = (float*)d_ws;                       // f32 wd[256] + bd
    _Float16*  wdf = (_Float16*)((char*)d_ws + 1280);    // f16 wd[256]
    _Float16*  tbl = (_Float16*)((char*)d_ws + 2048);    // f16 table
    const size_t need = 2048 + (size_t)nNodes * D * 2;

    if (ws_size >= need) {
        prep<<<6144, 256, 0, stream>>>((const float4v*)h, (half8*)tbl, nv16,
                                       W1, b1, W2, b2, W3, b3, wc, wdf);
        const int ngroups = (E + 15) / 16;
        edge_mfma<<<2048, 256, 0, stream>>>(tbl, edges, wc, wdf, out, E, ngroups);
    } else {
        prep<<<1, 256, 0, stream>>>((const float4v*)h, (half8*)wc /*unused*/, 0,
                                    W1, b1, W2, b2, W3, b3, wc, wdf);
        edge_predict_f32<<<2048, 256, 0, stream>>>(h, edges, wc, out, E);
    }
}

// Round 9
// 312.724 us; speedup vs baseline: 1.0245x; 1.0245x over previous
//
#include <hip/hip_runtime.h>
#include <hip/hip_bf16.h>

// EdgePredict: out = softmax((h[u]*h[v]) @ W1 @ W2 @ W3 + biases)
// R0: linear MLP chain collapses to wd[256] + bd; softmax2 = sigmoid(diff).
// R2: f16 table in ws halves gather bytes.
// R4: MFMA dot products, 16 edges/wave-group -> edge kernel at the 64B-line
//     request ceiling (16.25 lines/edge @ 117-118 G lines/s, the max rate
//     observed across 9 kernel shapes; MfmaUtil 2.3%, VALUBusy 6%).
// R5/R6: reorder passes (sort/binning) cost >=100 us to save 35 -> dead end.
// R7: nt-load fp32 h (single-use) + nt-store table + grid 8192 prep = best
//     measured total (313.4 us).
// R8 post-mortem: 64B/iter prep + grid 6144 regressed prep by ~13 us; the
//     nt-store's +6 us edge penalty is cheaper than its -13 us prep win.
// R9: lock the R7 optimum. Structural floor: 16 lines/edge (2x512 B f16
//     rows, all consumed), fp8/12-bit fail accuracy, reordering net-negative,
//     ~140 us harness overhead invariant. This is the roofline configuration.

#define D 256

typedef _Float16 half8 __attribute__((ext_vector_type(8)));
typedef float float4v __attribute__((ext_vector_type(4)));

// ---------------------------------------------------------------------------
// prep: collapse weights (block 0) + f32 -> f16 table (nt streaming).
// ws layout: [0,1152) wc f32 (wd[256], bd at 256); [1280,1792) wdf f16;
//            [2048,...) f16 table, 512 B/row.
// ---------------------------------------------------------------------------
__global__ __launch_bounds__(256) void prep(
    const float4v* __restrict__ h, half8* __restrict__ tb, int nv8,
    const float* __restrict__ W1, const float* __restrict__ b1,
    const float* __restrict__ W2, const float* __restrict__ b2,
    const float* __restrict__ W3, const float* __restrict__ b3,
    float* __restrict__ wc, _Float16* __restrict__ wdf)
{
    if (blockIdx.x == 0) {
        __shared__ float T[128][2];  // T = W2 @ W3
        const int t = threadIdx.x;
        {
            const int j = t >> 1, c = t & 1;
            float s = 0.f;
            #pragma unroll 8
            for (int k = 0; k < 64; ++k) s += W2[j * 64 + k] * W3[k * 2 + c];
            T[j][c] = s;
        }
        __syncthreads();
        float s0 = 0.f, s1 = 0.f;
        #pragma unroll 8
        for (int j = 0; j < 128; ++j) {
            const float w = W1[t * 128 + j];
            s0 += w * T[j][0];
            s1 += w * T[j][1];
        }
        const float wd = s1 - s0;
        wc[t]  = wd;
        wdf[t] = (_Float16)wd;
        if (t == 0) {
            float f0 = b3[0], f1 = b3[1];
            for (int j = 0; j < 128; ++j) { f0 += b1[j] * T[j][0]; f1 += b1[j] * T[j][1]; }
            for (int k = 0; k < 64; ++k)  { f0 += b2[k] * W3[k * 2 + 0]; f1 += b2[k] * W3[k * 2 + 1]; }
            wc[256] = f1 - f0;  // bd
        }
    }

    const int gstride = gridDim.x * blockDim.x;
    for (int i = blockIdx.x * blockDim.x + threadIdx.x; i < nv8; i += gstride) {
        const float4v f0 = __builtin_nontemporal_load(&h[2 * i]);
        const float4v f1 = __builtin_nontemporal_load(&h[2 * i + 1]);
        half8 o;
        o[0] = (_Float16)f0.x; o[1] = (_Float16)f0.y;
        o[2] = (_Float16)f0.z; o[3] = (_Float16)f0.w;
        o[4] = (_Float16)f1.x; o[5] = (_Float16)f1.y;
        o[6] = (_Float16)f1.z; o[7] = (_Float16)f1.w;
        __builtin_nontemporal_store(o, &tb[i]);
    }
}

// ---------------------------------------------------------------------------
// MFMA edge kernel (measured at the line-request ceiling):
// 16 edges per wave-group. A[m][k] = tbl[u_m][k]*wd[k] (m=lane&15,
// k=quad*8+j), B[k][n] = tbl[v_n][k]. Logit-diffs = diag(C): lane with
// quad==(m>>2), reg m&3.
// ---------------------------------------------------------------------------
__global__ __launch_bounds__(256) void edge_mfma(
    const _Float16* __restrict__ tbl, const int2* __restrict__ edges,
    const float* __restrict__ wc, const _Float16* __restrict__ wdf,
    float2* __restrict__ out, int E, int ngroups)
{
    const int lane = threadIdx.x & 63;
    const int m    = lane & 15;
    const int quad = lane >> 4;
    const int wid  = blockIdx.x * (blockDim.x >> 6) + (threadIdx.x >> 6);
    const int nw   = gridDim.x * (blockDim.x >> 6);

    const float bd = wc[256];
    const bool diag = (quad == (m >> 2));

    // loop-invariant wd fragments (32 VGPRs)
    half8 wq[8];
    {
        const half8* wp = (const half8*)(wdf + quad * 8);
        #pragma unroll
        for (int s = 0; s < 8; ++s) wq[s] = wp[4 * s];
    }

    for (int g = wid; g < ngroups; g += nw) {
        const int em = g * 16 + m;
        const int2 ed = edges[min(em, E - 1)];
        const half8* pa = (const half8*)(tbl + (size_t)ed.x * D + quad * 8);
        const half8* pb = (const half8*)(tbl + (size_t)ed.y * D + quad * 8);

        float4v acc = {0.f, 0.f, 0.f, 0.f};
        #pragma unroll
        for (int s = 0; s < 8; ++s) {
            const half8 a = pa[4 * s] * wq[s];   // 4x v_pk_mul_f16
            const half8 b = pb[4 * s];
            acc = __builtin_amdgcn_mfma_f32_16x16x32_f16(a, b, acc, 0, 0, 0);
        }

        if (diag && em < E) {
            const float d  = acc[m & 3] + bd;
            const float p1 = 1.0f / (1.0f + __expf(-d));
            out[em] = make_float2(1.0f - p1, p1);
        }
    }
}

// ---------------------------------------------------------------------------
// Fallback: fp32 gather + wave reduction (ws too small for the table)
// ---------------------------------------------------------------------------
__global__ __launch_bounds__(256) void edge_predict_f32(
    const float* __restrict__ h, const int2* __restrict__ edges,
    const float* __restrict__ wc, float2* __restrict__ out, int E)
{
    const int lane = threadIdx.x & 63;
    const int wid  = blockIdx.x * (blockDim.x >> 6) + (threadIdx.x >> 6);
    const int nw   = gridDim.x * (blockDim.x >> 6);
    const float4 wd = ((const float4*)wc)[lane];
    const float  bd = wc[256];
    for (int e = wid; e < E; e += nw) {
        const int2 ed = edges[e];
        const float4 a = ((const float4*)(h + (size_t)ed.x * D))[lane];
        const float4 b = ((const float4*)(h + (size_t)ed.y * D))[lane];
        float d = a.x * b.x * wd.x + a.y * b.y * wd.y + a.z * b.z * wd.z + a.w * b.w * wd.w;
        #pragma unroll
        for (int mm = 32; mm > 0; mm >>= 1) d += __shfl_xor(d, mm, 64);
        if (lane == 0) {
            const float p1 = 1.0f / (1.0f + __expf(-(d + bd)));
            out[e] = make_float2(1.0f - p1, p1);
        }
    }
}

// ---------------------------------------------------------------------------
extern "C" void kernel_launch(void* const* d_in, const int* in_sizes, int n_in,
                              void* d_out, int out_size, void* d_ws, size_t ws_size,
                              hipStream_t stream)
{
    const float* h     = (const float*)d_in[0];
    const int2*  edges = (const int2*)d_in[1];
    const float* W1    = (const float*)d_in[2];
    const float* b1    = (const float*)d_in[3];
    const float* W2    = (const float*)d_in[4];
    const float* b2    = (const float*)d_in[5];
    const float* W3    = (const float*)d_in[6];
    const float* b3    = (const float*)d_in[7];
    float2* out = (float2*)d_out;

    const int nNodes = in_sizes[0] / D;
    const int E      = in_sizes[1] / 2;
    const int nv8    = nNodes * (D / 8);

    float*     wc  = (float*)d_ws;                       // f32 wd[256] + bd
    _Float16*  wdf = (_Float16*)((char*)d_ws + 1280);    // f16 wd[256]
    _Float16*  tbl = (_Float16*)((char*)d_ws + 2048);    // f16 table
    const size_t need = 2048 + (size_t)nNodes * D * 2;

    if (ws_size >= need) {
        prep<<<8192, 256, 0, stream>>>((const float4v*)h, (half8*)tbl, nv8,
                                       W1, b1, W2, b2, W3, b3, wc, wdf);
        const int ngroups = (E + 15) / 16;
        edge_mfma<<<2048, 256, 0, stream>>>(tbl, edges, wc, wdf, out, E, ngroups);
    } else {
        prep<<<1, 256, 0, stream>>>((const float4v*)h, (half8*)wc /*unused*/, 0,
                                    W1, b1, W2, b2, W3, b3, wc, wdf);
        edge_predict_f32<<<2048, 256, 0, stream>>>(h, edges, wc, out, E);
    }
}